// Round 8
// baseline (578.951 us; speedup 1.0000x reference)
//
#include <hip/hip_runtime.h>
#include <hip/hip_bf16.h>
#include <cstdint>
#include <cstddef>

using bf16 = __hip_bfloat16;
typedef __bf16 bf16x8 __attribute__((ext_vector_type(8)));
typedef float f32x4 __attribute__((ext_vector_type(4)));

// ---- constants for this problem ----
#define BB 16
#define TT 1024
#define DD 1024
#define EE 64
#define MREAL 16368   // (TT-1)*BB
#define MPAD  16384
#define NCHUNK 16
#define CHUNK 64

__device__ __forceinline__ void gload_lds16(const void* g, void* l) {
  __builtin_amdgcn_global_load_lds((const __attribute__((address_space(1))) void*)g,
                                   (__attribute__((address_space(3))) void*)l,
                                   16, 0, 0);
}

__device__ __forceinline__ float sigmoidf_(float x) {
  return 1.0f / (1.0f + __expf(-x));
}

// ---------------- fp32 -> bf16 weight conversion (8 elems/thread, 16B store) ----
__global__ void f2b(const float* __restrict__ src, bf16* __restrict__ dst, int n) {
  int i = (blockIdx.x * blockDim.x + threadIdx.x) * 8;
  if (i < n) {
    float4 v0 = *reinterpret_cast<const float4*>(src + i);
    float4 v1 = *reinterpret_cast<const float4*>(src + i + 4);
    alignas(16) bf16 tmp[8];
    tmp[0] = __float2bfloat16(v0.x); tmp[1] = __float2bfloat16(v0.y);
    tmp[2] = __float2bfloat16(v0.z); tmp[3] = __float2bfloat16(v0.w);
    tmp[4] = __float2bfloat16(v1.x); tmp[5] = __float2bfloat16(v1.y);
    tmp[6] = __float2bfloat16(v1.z); tmp[7] = __float2bfloat16(v1.w);
    *reinterpret_cast<float4*>(dst + i) = *reinterpret_cast<const float4*>(tmp);
  }
}

// ---------------- EMA pass 1: chunk-local endpoints ----------------
__global__ void ema_ends(const float* __restrict__ seq, const float* __restrict__ beta_raw,
                         float* __restrict__ ends) {
  int tid = blockIdx.x * blockDim.x + threadIdx.x;
  int d = tid & (DD - 1);
  int b = (tid >> 10) & (BB - 1);
  int c = tid >> 14;
  float beta = sigmoidf_(beta_raw[d]);
  int t0 = c * CHUNK;
  int len = min(CHUNK, (TT - 1) - t0);
  const float* p = seq + (size_t)b * TT * DD + (size_t)t0 * DD + d;
  float h = 0.0f;
#pragma unroll 8
  for (int j = 0; j < len; ++j) h = fmaf(beta, h, p[(size_t)j * DD]);
  ends[tid] = h;
}

// ---------------- EMA pass 2: carry combine (per chain) ----------------
__global__ void ema_carry(const float* __restrict__ ends, const float* __restrict__ beta_raw,
                          float* __restrict__ carry) {
  int tid = blockIdx.x * blockDim.x + threadIdx.x;
  int d = tid & (DD - 1);
  float beta = sigmoidf_(beta_raw[d]);
  float bl = beta;
  bl *= bl; bl *= bl; bl *= bl; bl *= bl; bl *= bl; bl *= bl;  // beta^64
  float run = 0.0f;
#pragma unroll
  for (int c = 0; c < NCHUNK; ++c) {
    carry[c * (BB * DD) + tid] = run;
    run = ends[c * (BB * DD) + tid] + bl * run;
  }
}

// ---------------- EMA pass 3: recompute + write A = [x | h] in bf16 ----------------
__global__ void ema_write(const float* __restrict__ seq, const float* __restrict__ beta_raw,
                          const float* __restrict__ carry, bf16* __restrict__ A) {
  int tid = blockIdx.x * blockDim.x + threadIdx.x;
  int d = tid & (DD - 1);
  int b = (tid >> 10) & (BB - 1);
  int c = tid >> 14;
  float beta = sigmoidf_(beta_raw[d]);
  int t0 = c * CHUNK;
  int len = min(CHUNK, (TT - 1) - t0);
  const float* p = seq + (size_t)b * TT * DD + (size_t)t0 * DD + d;
  float h = carry[tid];
#pragma unroll 4
  for (int j = 0; j < len; ++j) {
    float x = p[(size_t)j * DD];
    h = fmaf(beta, h, x);
    size_t m = (size_t)(t0 + j) * BB + b;
    A[m * (2 * DD) + d]      = __float2bfloat16(x);
    A[m * (2 * DD) + DD + d] = __float2bfloat16(h);
  }
}

// =====================================================================
// 256x256 GEMM, 16x16x32 MFMA, 2-PHASE-AHEAD fragment pipeline.
// (Identical resubmission of R7 — container-infra failure pattern: every
// new source fails once and passes on resubmit (R3->R4, R5->R6). Ledger
// and LDS WAR audit re-verified; no functional change.)
//
// R6 post-mortem (corrected pipe model): per K-tile per SIMD the MFMA
// pipe needs 2484 cyc (128 mfma x 19.4 cyc); per CU the LDS read pipe
// needs 2313 cyc (192 ds_read_b128 x 12). Measured 4594 = sum: with
// 1-phase-ahead reads, the issue->consume window is one barrier (~50cy),
// so every phase stalls ~500cy waiting its reads drain (48 reads/phase
// x 12cy = 576), then runs 621cy MFMA. The lever is DISTANCE, not wait
// flavor: reads issued in phase k now feed phase k+2's MFMA, giving the
// LDS pipe 2 full phases (>=1300cy) to drain each phase's 32-64 reads
// under the MFMA of intervening phases.
//
// Per-tile schedule (fixed quadrants P0:a03*b01 P1:a03*b23 P2:a47*b23
// P3:a47*b01; each fragment read ONCE per tile, held in regs):
//   shadow(P0) = a47[0:2](q)      [consumed P2(q), 2-ahead]
//   shadow(P1) = a47[2:4](q)      [consumed P2(q), 1-ahead, only 4 reads]
//   shadow(P2) = a03(q+1)         [consumed P0(q+1), 2-ahead]
//   shadow(P3) = b01(q+1),b23(q+1)[consumed P0/P1(q+1), 1-2-ahead]
// Read distribution 4/4/8/8. b01 needs TWO register sets (loaded at
// P3(q) while b01(q) is consumed that same phase) -> bE/bO by parity.
// All other sets have >=1 full phase between last-use and overwrite.
//
// Staging unchanged: P0/P1 porch = A(q+1) halves -> dbuf d^1, P2/P3
// porch = B(q+2) halves -> dbuf d. Single counted vmcnt(2) per tile at
// P2 porch: after issuing B(q+2)h0, outstanding = B(q+1)x4 + A(q+1)x4 +
// B(q+2)h0x2 = 10; vmcnt(2) drains the 8 oldest -> A(q+1) and B(q+1)
// landed before any tile-(q+1) shadow read. Never drains to 0 in-loop.
// Compiler's automatic counted lgkmcnt handles read->MFMA ordering
// (data is 1-2 phases old -> waits are ~free). No blanket lgkm pins.
//
// LDS race audit (all transitions): a region's last ds_read is consumed
// by an MFMA >=1 barrier before the region's restage issue point; the
// counted lgkm wait at that MFMA proves the read drained. Tail: clamped
// kA/kB restage identical bytes over live regions (value-safe) and the
// garbage shadow reads land in never-consumed registers.
// Swizzle + staging + 16x16 read pattern identical to R1 (0 conflicts).
// =====================================================================

#define RD_A03(d)                                                            \
  _Pragma("unroll")                                                          \
  for (int f = 0; f < 4; ++f)                                                \
    _Pragma("unroll")                                                        \
    for (int s = 0; s < 2; ++s)                                              \
      a03[f][s] = *reinterpret_cast<const bf16x8*>(                          \
          &lds[(d) * 32768 + ArdB + f * 1024 + roff[s]]);

#define RD_A47H(d, f0)                                                       \
  _Pragma("unroll")                                                          \
  for (int ff = 0; ff < 2; ++ff)                                             \
    _Pragma("unroll")                                                        \
    for (int s = 0; s < 2; ++s)                                              \
      a47[(f0) + ff][s] = *reinterpret_cast<const bf16x8*>(                  \
          &lds[(d) * 32768 + ArdB + ((f0) + ff + 4) * 1024 + roff[s]]);

#define RD_B2(d, arr, jbase)                                                 \
  _Pragma("unroll")                                                          \
  for (int jj = 0; jj < 2; ++jj)                                             \
    _Pragma("unroll")                                                        \
    for (int s = 0; s < 2; ++s)                                              \
      arr[jj][s] = *reinterpret_cast<const bf16x8*>(                         \
          &lds[(d) * 32768 + BrdB + ((jbase) + jj) * 1024 + roff[s]]);

#define STAGE_A(d, h, kq)                                                    \
  {                                                                          \
    _Pragma("unroll")                                                        \
    for (int t = 0; t < 2; ++t)                                              \
      gload_lds16(gA + ((size_t)((h) * 128 + t * 8) * K + (kq) * 64),        \
                  &lds[(d) * 32768 + (h) * 8192 + stbase + t * 512]);        \
  }

#define STAGE_B(d, h, kq)                                                    \
  {                                                                          \
    _Pragma("unroll")                                                        \
    for (int t = 0; t < 2; ++t)                                              \
      gload_lds16(gB + ((size_t)((h) * 128 + t * 8) * K + (kq) * 64),        \
                  &lds[(d) * 32768 + 16384 + (h) * 8192 + stbase + t * 512]); \
  }

#define MFMA_P(fb, aarr, j0, barr)                                           \
  _Pragma("unroll")                                                          \
  for (int s = 0; s < 2; ++s)                                                \
    _Pragma("unroll")                                                        \
    for (int f = 0; f < 4; ++f)                                              \
      _Pragma("unroll")                                                      \
      for (int j = 0; j < 2; ++j)                                            \
        acc[(fb) + f][(j0) + j] = __builtin_amdgcn_mfma_f32_16x16x32_bf16(   \
            aarr[f][s], barr[j][s], acc[(fb) + f][(j0) + j], 0, 0, 0);

#define PH_OPEN()                                                            \
  __builtin_amdgcn_s_barrier();                                              \
  __builtin_amdgcn_s_setprio(1);

#define PH_SHDW()                                                            \
  __builtin_amdgcn_s_setprio(0);                                             \
  __builtin_amdgcn_sched_barrier(0);

#define PH_CLOSE()                                                           \
  __builtin_amdgcn_sched_barrier(0);                                         \
  __builtin_amdgcn_s_barrier();

#define KTILE2(d, bcur, bnext)                                               \
  {                                                                          \
    const int kA = (q + 1 < NT) ? (q + 1) : (NT - 1);                        \
    const int kB = (q + 2 < NT) ? (q + 2) : (NT - 1);                        \
    /* P0: a03 x b01 */                                                      \
    STAGE_A((d) ^ 1, 0, kA);                                                 \
    PH_OPEN(); MFMA_P(0, a03, 0, bcur); PH_SHDW(); RD_A47H(d, 0); PH_CLOSE(); \
    /* P1: a03 x b23 */                                                      \
    STAGE_A((d) ^ 1, 1, kA);                                                 \
    PH_OPEN(); MFMA_P(0, a03, 2, b23); PH_SHDW(); RD_A47H(d, 2); PH_CLOSE(); \
    /* P2: a47 x b23 */                                                      \
    STAGE_B(d, 0, kB);                                                       \
    asm volatile("s_waitcnt vmcnt(2)" ::: "memory");                         \
    PH_OPEN(); MFMA_P(4, a47, 2, b23); PH_SHDW(); RD_A03((d) ^ 1); PH_CLOSE(); \
    /* P3: a47 x b01 */                                                      \
    STAGE_B(d, 1, kB);                                                       \
    PH_OPEN(); MFMA_P(4, a47, 0, bcur); PH_SHDW();                           \
    RD_B2((d) ^ 1, bnext, 0); RD_B2((d) ^ 1, b23, 2); PH_CLOSE();            \
    ++q;                                                                     \
  }

template <bool RELU, bool DUAL_OUT>
__global__ __launch_bounds__(512, 2)
void gemm8(const bf16* __restrict__ A, const bf16* __restrict__ B,
           const float* __restrict__ bias, bf16* __restrict__ outb,
           float* __restrict__ outf, int N, int K) {
  __shared__ bf16 lds[65536];  // 128 KiB
  const int tid  = threadIdx.x;
  const int wave = tid >> 6;
  const int lane = tid & 63;
  const int wm = wave >> 2;  // 0..1 (M half of block)
  const int wn = wave & 3;   // 0..3 (N quarter)

  // XCD-aware bijective swizzle (nwg % 8 == 0 for both launches)
  const int gx   = gridDim.x;
  const int nwg  = gx * gridDim.y;
  const int orig = blockIdx.y * gx + blockIdx.x;
  const int swz  = (orig & 7) * (nwg >> 3) + (orig >> 3);
  const int bm = (swz / gx) * 256;
  const int bn = (swz % gx) * 256;

  // staging: wave w, instr t covers 8 rows (w*16 + t*8 .. +8) x 128 B of a
  // half-tile; per-lane global source pre-swizzled: logical cg = (l&7)^(l>>3)
  const int srow = lane >> 3;
  const int scg  = (lane & 7) ^ srow;
  const bf16* gA = A + (size_t)(bm + wave * 16 + srow) * K + scg * 8;
  const bf16* gB = B + (size_t)(bn + wave * 16 + srow) * K + scg * 8;
  const int stbase = wave * 1024;  // (wave*16 rows) * 64 elems

  // ds_read per-lane offsets (elements): row (l&15), k-granule (s*4+(l>>4)),
  // physical cg = granule ^ (row&7)   [R1-verified: 0 bank conflicts]
  int roff[2];
#pragma unroll
  for (int s = 0; s < 2; ++s)
    roff[s] = (lane & 15) * 64 + (((s * 4 + (lane >> 4)) ^ (lane & 7)) * 8);
  const int ArdB = wm * 8192;                                   // A half = wm
  const int BrdB = 16384 + (wn >> 1) * 8192 + (wn & 1) * 4096;  // B half + 64-row sub

  f32x4 acc[8][4] = {};
  bf16x8 a03[4][2], a47[4][2], bE[2][2], bO[2][2], b23[2][2];
  const int NT = K >> 6;

  // ---- prologue: stage A(0), B(0), B(1); land tile 0, keep B(1) in flight ----
  STAGE_A(0, 0, 0);
  STAGE_A(0, 1, 0);
  STAGE_B(0, 0, 0);
  STAGE_B(0, 1, 0);
  STAGE_B(1, 0, 1);
  STAGE_B(1, 1, 1);
  asm volatile("s_waitcnt vmcnt(4)" ::: "memory");
  __builtin_amdgcn_s_barrier();
  // pre-load tile-0 P0/P1 operands: a03(0), b01(0)->bE, b23(0)
  RD_A03(0);
  RD_B2(0, bE, 0);
  RD_B2(0, b23, 2);

  int q = 0;
#pragma unroll 1
  for (int it = 0; it < (NT >> 1); ++it) {
    KTILE2(0, bE, bO);
    KTILE2(1, bO, bE);
  }
  asm volatile("s_waitcnt vmcnt(0)" ::: "memory");  // drain tail garbage stages

  // ---- epilogue: 16x16 C/D layout: n = lane&15, m = (lane>>4)*4 + r ----
  float bv[4];
  int   ncol[4];
#pragma unroll
  for (int j = 0; j < 4; ++j) {
    ncol[j] = bn + wn * 64 + j * 16 + (lane & 15);
    bv[j]   = bias[ncol[j]];
  }
#pragma unroll
  for (int f = 0; f < 8; ++f) {
    const int m0 = bm + wm * 128 + f * 16 + (lane >> 4) * 4;
#pragma unroll
    for (int j = 0; j < 4; ++j) {
      const int n = ncol[j];
#pragma unroll
      for (int r = 0; r < 4; ++r) {
        float v = acc[f][j][r] + bv[j];
        if (RELU) v = fmaxf(v, 0.0f);
        const int m = m0 + r;
        outb[(size_t)m * N + n] = __float2bfloat16(v);
        if (DUAL_OUT) {
          if (m < MREAL) outf[(size_t)m * N + n] = v;
        }
      }
    }
  }
}

// ---------------- router GEMM: logits = (Xhat @ Ww^T + Wb) * pi ----------------
// A: (MPAD, 1024) bf16, B: (64, 1024) bf16. 64x64 tile, 256 threads, 16x16x32.
__global__ __launch_bounds__(256)
void gemm_router(const bf16* __restrict__ A, const bf16* __restrict__ B,
                 const float* __restrict__ Wb, const float* __restrict__ pi,
                 float* __restrict__ out) {
  const int K = DD;
  __shared__ alignas(16) bf16 As[64 * 32];
  __shared__ alignas(16) bf16 Bs[64 * 32];
  const int tid  = threadIdx.x;
  const int wave = tid >> 6;
  const int lane = tid & 63;
  const int bm = blockIdx.x * 64;
  const int srow = wave * 16 + (lane >> 2);
  const int scol = (lane & 3) * 8;
  const bf16* gA = A + (size_t)(bm + srow) * K + scol;
  const bf16* gB = B + (size_t)srow * K + scol;
  bf16* lA = &As[srow * 32 + scol];
  bf16* lB = &Bs[srow * 32 + scol];
  const int lr = lane & 15;
  const int quad = lane >> 4;
  f32x4 acc[4] = {};
  for (int k0 = 0; k0 < K; k0 += 32) {
    __syncthreads();
    gload_lds16(gA + k0, lA);
    gload_lds16(gB + k0, lB);
    __syncthreads();
    bf16x8 af = *reinterpret_cast<const bf16x8*>(&As[(wave * 16 + lr) * 32 + quad * 8]);
#pragma unroll
    for (int j = 0; j < 4; ++j) {
      bf16x8 bf_ = *reinterpret_cast<const bf16x8*>(&Bs[(j * 16 + lr) * 32 + quad * 8]);
      acc[j] = __builtin_amdgcn_mfma_f32_16x16x32_bf16(af, bf_, acc[j], 0, 0, 0);
    }
  }
#pragma unroll
  for (int j = 0; j < 4; ++j) {
    const int e = j * 16 + lr;
    const float wb = Wb[e], pv = pi[e];
#pragma unroll
    for (int r = 0; r < 4; ++r) {
      const int m = bm + wave * 16 + quad * 4 + r;
      if (m < MREAL) out[(size_t)m * EE + e] = (acc[j][r] + wb) * pv;
    }
  }
}

extern "C" void kernel_launch(void* const* d_in, const int* in_sizes, int n_in,
                              void* d_out, int out_size, void* d_ws, size_t ws_size,
                              hipStream_t stream) {
  const float* seq      = (const float*)d_in[0];
  const float* pi       = (const float*)d_in[1];
  const float* beta_raw = (const float*)d_in[2];
  const float* p1_w     = (const float*)d_in[3];
  const float* p1_b     = (const float*)d_in[4];
  const float* p2_w     = (const float*)d_in[5];
  const float* p2_b     = (const float*)d_in[6];
  const float* W_w      = (const float*)d_in[7];
  const float* W_b      = (const float*)d_in[8];

  // workspace layout (bytes); Xhat_bf16 aliases A (A dead after GEMM1)
  constexpr size_t A_off    = 0;
  constexpr size_t A_sz     = (size_t)MPAD * 2 * DD * sizeof(bf16);   //  64 MiB
  constexpr size_t W1_off   = A_off + A_sz;
  constexpr size_t W1_sz    = (size_t)4 * DD * 2 * DD * sizeof(bf16); //  16 MiB
  constexpr size_t HID_off  = W1_off + W1_sz;
  constexpr size_t HID_sz   = (size_t)MPAD * 4 * DD * sizeof(bf16);   // 128 MiB
  constexpr size_t W2_off   = HID_off + HID_sz;
  constexpr size_t W2_sz    = (size_t)DD * 4 * DD * sizeof(bf16);     //   8 MiB
  constexpr size_t W3_off   = W2_off + W2_sz;
  constexpr size_t W3_sz    = (size_t)EE * DD * sizeof(bf16);
  constexpr size_t ENDS_off = W3_off + W3_sz;
  constexpr size_t ENDS_sz  = (size_t)NCHUNK * BB * DD * sizeof(float);
  constexpr size_t CARRY_off = ENDS_off + ENDS_sz;

  char* ws = (char*)d_ws;
  bf16*  Abuf = (bf16*)(ws + A_off);
  bf16*  W1   = (bf16*)(ws + W1_off);
  bf16*  HID  = (bf16*)(ws + HID_off);
  bf16*  W2   = (bf16*)(ws + W2_off);
  bf16*  W3   = (bf16*)(ws + W3_off);
  float* ENDS = (float*)(ws + ENDS_off);
  float* CARRY = (float*)(ws + CARRY_off);
  bf16*  XH   = (bf16*)(ws + A_off);  // alias of A

  float* out_logits = (float*)d_out;
  float* out_xhat   = out_logits + (size_t)MREAL * EE;

  // 1) weights -> bf16
  f2b<<<(4 * DD * 2 * DD / 8 + 255) / 256, 256, 0, stream>>>(p1_w, W1, 4 * DD * 2 * DD);
  f2b<<<(DD * 4 * DD / 8 + 255) / 256, 256, 0, stream>>>(p2_w, W2, DD * 4 * DD);
  f2b<<<(EE * DD / 8 + 255) / 256, 256, 0, stream>>>(W_w, W3, EE * DD);

  // 2) EMA scan (chunked 3-pass) -> A = [x | h] bf16
  ema_ends<<<NCHUNK * BB * DD / 256, 256, 0, stream>>>(seq, beta_raw, ENDS);
  ema_carry<<<BB * DD / 256, 256, 0, stream>>>(ENDS, beta_raw, CARRY);
  ema_write<<<NCHUNK * BB * DD / 256, 256, 0, stream>>>(seq, beta_raw, CARRY, Abuf);
  (void)hipMemsetAsync(ws + A_off + (size_t)MREAL * 2 * DD * sizeof(bf16), 0,
                       (size_t)(MPAD - MREAL) * 2 * DD * sizeof(bf16), stream);

  // 3) GEMM1: hid = relu(A @ p1_w^T + b1)   (16384 x 4096, K=2048)
  gemm8<true, false><<<dim3(4 * DD / 256, MPAD / 256), 512, 0, stream>>>(
      Abuf, W1, p1_b, HID, nullptr, 4 * DD, 2 * DD);

  // 4) GEMM2: x_hat = hid @ p2_w^T + b2     (16384 x 1024, K=4096) -> f32 out + bf16 ws
  gemm8<false, true><<<dim3(DD / 256, MPAD / 256), 512, 0, stream>>>(
      HID, W2, p2_b, XH, out_xhat, DD, 4 * DD);

  // 5) GEMM3: logits = (x_hat @ W_w^T + W_b) * pi   (16368 x 64, K=1024)
  gemm_router<<<MPAD / 64, 256, 0, stream>>>(XH, W3, W_b, pi, out_logits);
}